// Round 8
// baseline (122.094 us; speedup 1.0000x reference)
//
#include <hip/hip_runtime.h>
#include <stdint.h>

#define NPTS   4096
#define NSKIP  16384
#define CCH    256
#define CSK    128
#define DIN    384
#define HDIM   256
#define BIGF   1e10f

typedef unsigned short u16;
typedef __attribute__((ext_vector_type(8))) short short8;
typedef __attribute__((ext_vector_type(4))) float floatx4;

__device__ __forceinline__ u16 f2bf(float f) {
    union { float f; uint32_t u; } c; c.f = f;
    uint32_t u = c.u;
    return (u16)((u + 0x7FFFu + ((u >> 16) & 1u)) >> 16);
}

// Pack (non-negative fp32 dist, idx) into a positive double whose numeric
// order == (dist, idx) lexicographic order (exact top_k tie semantics).
__device__ __forceinline__ double pkkey(float d, int j) {
    return __hiloint2double(__float_as_int(d), j);
}

// ---------------------------------------------------------------------------
// prep: blocks 0-47 pack W1 (KT=12), 48-79 pack W2 (KT=8) into MFMA
// B-fragment layout; blocks 48-63 also build pos4; block 0 builds ranges.
// ---------------------------------------------------------------------------
__global__ __launch_bounds__(256) void prep_kernel(
    const float* __restrict__ W1, const float* __restrict__ W2,
    u16* __restrict__ W1p, u16* __restrict__ W2p,
    const float* __restrict__ pos, float4* __restrict__ pos4,
    const int* __restrict__ batch, int* __restrict__ range)
{
    const int bid = blockIdx.x;
    const int t = threadIdx.x;

    const float* W = (bid < 48) ? W1 : W2;
    u16* Wp       = (bid < 48) ? W1p : W2p;
    const int KT  = (bid < 48) ? 12 : 8;
    const int g   = ((bid < 48) ? bid : (bid - 48)) * 256 + t;

    const int lane = g & 63;
    const int kt = (g >> 6) % KT;
    const int nt = (g >> 6) / KT;
    const int kbase = kt * 32 + (lane >> 4) * 8;
    const int n = nt * 16 + (lane & 15);
    u16 v[8];
#pragma unroll
    for (int j = 0; j < 8; ++j) v[j] = f2bf(W[(size_t)(kbase + j) * HDIM + n]);
#pragma unroll
    for (int j = 0; j < 8; ++j) Wp[(size_t)g * 8 + j] = v[j];

    if (bid >= 48 && bid < 64) {
        const int p = (bid - 48) * 256 + t;
        pos4[p] = make_float4(pos[p * 3 + 0], pos[p * 3 + 1], pos[p * 3 + 2], 0.0f);
    }

    if (bid == 0) {
        for (int j = t * 16; j < t * 16 + 16; ++j) {
            if (j == 0) {
                const int b0 = batch[0];
                for (int b = 0; b <= b0; ++b) range[b] = 0;
            } else {
                const int bp = batch[j - 1], bj = batch[j];
                for (int b = bp + 1; b <= bj; ++b) range[b] = j;
            }
            if (j == NPTS - 1) {
                const int bl = batch[NPTS - 1];
                for (int b = bl + 1; b <= 4; ++b) range[b] = NPTS;
            }
        }
    }
}

// ---------------------------------------------------------------------------
// KNN v5: 64 threads (one full wave) per fine point, 4 points / 256-thr
// block. Wave lanes scan stride-64 -> one fully-coalesced 1KB float4 load
// per wave-iteration (~16 iters). Branchless f64-key top-3 bubble, then a
// 6-step shfl_xor butterfly. _rn ops keep selection exact vs np reference.
// ---------------------------------------------------------------------------
__global__ __launch_bounds__(256) void knn_kernel(
    const float4* __restrict__ pos4, const int* __restrict__ range,
    const float* __restrict__ pos_skip, const int* __restrict__ batch_skip,
    int* __restrict__ idx3, float* __restrict__ w3)
{
    const int t = threadIdx.x;
    const int i = blockIdx.x * 4 + (t >> 6);
    const int sub = t & 63;
    const int b = batch_skip[i];
    const int start = range[b], end = range[b + 1];

    const float px = pos_skip[i * 3 + 0];
    const float py = pos_skip[i * 3 + 1];
    const float pz = pos_skip[i * 3 + 2];

    const double BIGKEY = pkkey(BIGF, 0x7FFFFFFF);
    double k0 = BIGKEY, k1 = BIGKEY, k2 = BIGKEY;

    for (int j = start + sub; j < end; j += 64) {
        const float4 q = pos4[j];
        const float dx = __fsub_rn(px, q.x);
        const float dy = __fsub_rn(py, q.y);
        const float dz = __fsub_rn(pz, q.z);
        const float dd = __fadd_rn(__fadd_rn(__fmul_rn(dx, dx), __fmul_rn(dy, dy)),
                                   __fmul_rn(dz, dz));
        const double kk = pkkey(dd, j);
        const double u0 = fmax(k0, kk); k0 = fmin(k0, kk);
        const double u1 = fmax(k1, u0); k1 = fmin(k1, u0);
        k2 = fmin(k2, u1);
    }

#pragma unroll
    for (int m = 1; m < 64; m <<= 1) {
        const double o0 = __shfl_xor(k0, m);
        const double o1 = __shfl_xor(k1, m);
        const double o2 = __shfl_xor(k2, m);
        double u0 = fmax(k0, o0); k0 = fmin(k0, o0);
        double u1 = fmax(k1, u0); k1 = fmin(k1, u0);
        k2 = fmin(k2, u1);
        u1 = fmax(k1, o1); k1 = fmin(k1, o1);
        k2 = fmin(k2, u1);
        k2 = fmin(k2, o2);
    }

    if (sub == 0) {
        const float d0 = __int_as_float(__double2hiint(k0));
        const float d1 = __int_as_float(__double2hiint(k1));
        const float d2 = __int_as_float(__double2hiint(k2));
        const float w0 = 1.0f / fmaxf(d0, 1e-16f);
        const float w1 = 1.0f / fmaxf(d1, 1e-16f);
        const float w2 = 1.0f / fmaxf(d2, 1e-16f);
        const float inv = 1.0f / (w0 + w1 + w2);
        idx3[i * 3 + 0] = __double2loint(k0);
        idx3[i * 3 + 1] = __double2loint(k1);
        idx3[i * 3 + 2] = __double2loint(k2);
        w3[i * 3 + 0] = w0 * inv; w3[i * 3 + 1] = w1 * inv; w3[i * 3 + 2] = w2 * inv;
    }
}

// ---------------------------------------------------------------------------
// Fused MLP v2: 64 rows per block (256 blocks). interp+concat -> LDS
// A(bf16)[64x392] -> MFMA GEMM1 (K=384, 4 m-tiles, B-frag loaded once per
// (kt,nt) feeding 4 MFMAs) -> h(bf16)[64x264] -> GEMM2 (K=256) -> out + tail.
// Halves W L2 traffic vs 32-row version and amortizes per-block overheads.
// ---------------------------------------------------------------------------
__global__ __launch_bounds__(256) void fused_mlp_kernel(
    const float* __restrict__ x, const float* __restrict__ x_skip,
    const int* __restrict__ idx3, const float* __restrict__ w3,
    const u16* __restrict__ W1p, const float* __restrict__ b1,
    const u16* __restrict__ W2p, const float* __restrict__ b2,
    const float* __restrict__ pos_skip, const int* __restrict__ batch_skip,
    float* __restrict__ out)
{
    __shared__ u16 sA[64 * 392];   // 50176 B; reused as h[64][264]
    const int t = threadIdx.x;
    const int row0 = blockIdx.x * 64;

    // --- interp: 64 rows x 64 float4 (256 fp32 cols each) ---
#pragma unroll
    for (int k = 0; k < 16; ++k) {
        const int g = t + 256 * k;
        const int row = g >> 6, c4 = g & 63;
        const int R = row0 + row;
        const int i0 = idx3[R * 3 + 0], i1 = idx3[R * 3 + 1], i2 = idx3[R * 3 + 2];
        const float w0 = w3[R * 3 + 0], w1 = w3[R * 3 + 1], w2 = w3[R * 3 + 2];
        const float4 v0 = *(const float4*)(x + (size_t)i0 * CCH + c4 * 4);
        const float4 v1 = *(const float4*)(x + (size_t)i1 * CCH + c4 * 4);
        const float4 v2 = *(const float4*)(x + (size_t)i2 * CCH + c4 * 4);
        const float a  = w0 * v0.x + w1 * v1.x + w2 * v2.x;
        const float bq = w0 * v0.y + w1 * v1.y + w2 * v2.y;
        const float cq = w0 * v0.z + w1 * v1.z + w2 * v2.z;
        const float dq = w0 * v0.w + w1 * v1.w + w2 * v2.w;
        uint2 pk;
        pk.x = (uint32_t)f2bf(a)  | ((uint32_t)f2bf(bq) << 16);
        pk.y = (uint32_t)f2bf(cq) | ((uint32_t)f2bf(dq) << 16);
        *(uint2*)(sA + row * 392 + c4 * 4) = pk;
    }
    // --- skip copy: 64 rows x 32 float4 (128 fp32 cols each) ---
#pragma unroll
    for (int k = 0; k < 8; ++k) {
        const int g = t + 256 * k;
        const int row = g >> 5, c4 = g & 31;
        const float4 v = *(const float4*)(x_skip + (size_t)(row0 + row) * CSK + c4 * 4);
        uint2 pk;
        pk.x = (uint32_t)f2bf(v.x) | ((uint32_t)f2bf(v.y) << 16);
        pk.y = (uint32_t)f2bf(v.z) | ((uint32_t)f2bf(v.w) << 16);
        *(uint2*)(sA + row * 392 + CCH + c4 * 4) = pk;
    }
    __syncthreads();

    const int wave = t >> 6, lane = t & 63;
    const int quad = lane >> 4, ml = lane & 15;

    // --- GEMM1: A[64x384] @ W1 -> h[64x256] ---
    floatx4 acc[4][4] = {};
    {
        const u16* aA = sA + ml * 392 + quad * 8;
        for (int kt = 0; kt < 12; ++kt) {
            short8 a0 = *(const short8*)(aA + kt * 32);
            short8 a1 = *(const short8*)(aA + 16 * 392 + kt * 32);
            short8 a2 = *(const short8*)(aA + 32 * 392 + kt * 32);
            short8 a3 = *(const short8*)(aA + 48 * 392 + kt * 32);
#pragma unroll
            for (int nt = 0; nt < 4; ++nt) {
                const int ntile = wave * 4 + nt;
                short8 bfr = *(const short8*)(W1p + (size_t)((ntile * 12 + kt) * 64 + lane) * 8);
                acc[0][nt] = __builtin_amdgcn_mfma_f32_16x16x32_bf16(a0, bfr, acc[0][nt], 0, 0, 0);
                acc[1][nt] = __builtin_amdgcn_mfma_f32_16x16x32_bf16(a1, bfr, acc[1][nt], 0, 0, 0);
                acc[2][nt] = __builtin_amdgcn_mfma_f32_16x16x32_bf16(a2, bfr, acc[2][nt], 0, 0, 0);
                acc[3][nt] = __builtin_amdgcn_mfma_f32_16x16x32_bf16(a3, bfr, acc[3][nt], 0, 0, 0);
            }
        }
    }
    __syncthreads();

    // --- h = relu(acc + b1) -> LDS bf16 [64 x 264] ---
#pragma unroll
    for (int mt = 0; mt < 4; ++mt) {
#pragma unroll
        for (int nt = 0; nt < 4; ++nt) {
            const int n = (wave * 4 + nt) * 16 + ml;
            const float bv = b1[n];
#pragma unroll
            for (int r = 0; r < 4; ++r) {
                const int m = mt * 16 + quad * 4 + r;
                sA[m * 264 + n] = f2bf(fmaxf(acc[mt][nt][r] + bv, 0.0f));
            }
        }
    }
    __syncthreads();

    // --- GEMM2: h[64x256] @ W2 -> out (fp32) ---
    floatx4 acc2[4][4] = {};
    {
        const u16* aH = sA + ml * 264 + quad * 8;
        for (int kt = 0; kt < 8; ++kt) {
            short8 a0 = *(const short8*)(aH + kt * 32);
            short8 a1 = *(const short8*)(aH + 16 * 264 + kt * 32);
            short8 a2 = *(const short8*)(aH + 32 * 264 + kt * 32);
            short8 a3 = *(const short8*)(aH + 48 * 264 + kt * 32);
#pragma unroll
            for (int nt = 0; nt < 4; ++nt) {
                const int ntile = wave * 4 + nt;
                short8 bfr = *(const short8*)(W2p + (size_t)((ntile * 8 + kt) * 64 + lane) * 8);
                acc2[0][nt] = __builtin_amdgcn_mfma_f32_16x16x32_bf16(a0, bfr, acc2[0][nt], 0, 0, 0);
                acc2[1][nt] = __builtin_amdgcn_mfma_f32_16x16x32_bf16(a1, bfr, acc2[1][nt], 0, 0, 0);
                acc2[2][nt] = __builtin_amdgcn_mfma_f32_16x16x32_bf16(a2, bfr, acc2[2][nt], 0, 0, 0);
                acc2[3][nt] = __builtin_amdgcn_mfma_f32_16x16x32_bf16(a3, bfr, acc2[3][nt], 0, 0, 0);
            }
        }
    }

#pragma unroll
    for (int mt = 0; mt < 4; ++mt) {
#pragma unroll
        for (int nt = 0; nt < 4; ++nt) {
            const int n = (wave * 4 + nt) * 16 + ml;
            const float bv = b2[n];
#pragma unroll
            for (int r = 0; r < 4; ++r) {
                const int m = row0 + mt * 16 + quad * 4 + r;
                out[(size_t)m * HDIM + n] = fmaxf(acc2[mt][nt][r] + bv, 0.0f);
            }
        }
    }

    // --- tail: 256 flat elems per block (256 blocks x 256 = 65536 exactly) ---
    {
        const int e = blockIdx.x * 256 + t;
        const size_t base = (size_t)NSKIP * HDIM;
        if (e < NSKIP * 3) out[base + e] = pos_skip[e];
        else               out[base + e] = (float)batch_skip[e - NSKIP * 3];
    }
}

extern "C" void kernel_launch(void* const* d_in, const int* in_sizes, int n_in,
                              void* d_out, int out_size, void* d_ws, size_t ws_size,
                              hipStream_t stream) {
    const float* x         = (const float*)d_in[0];
    const float* pos       = (const float*)d_in[1];
    const int*   batch     = (const int*)d_in[2];
    const float* x_skip    = (const float*)d_in[3];
    const float* pos_skip  = (const float*)d_in[4];
    const int*   batch_skip= (const int*)d_in[5];
    const float* W1        = (const float*)d_in[6];
    const float* b1        = (const float*)d_in[7];
    const float* W2        = (const float*)d_in[8];
    const float* b2        = (const float*)d_in[9];
    float* out = (float*)d_out;

    // ws layout:
    char* ws = (char*)d_ws;
    u16*    W1p   = (u16*)ws;                      // 196608 B
    u16*    W2p   = (u16*)(ws + 196608);           // 131072 B
    int*    range = (int*)(ws + 327680);           // 32 B
    float4* pos4  = (float4*)(ws + 327712);        // 65536 B
    int*    idx3  = (int*)(ws + 393248);           // 196608 B
    float*  w3    = (float*)(ws + 589856);         // 196608 B

    prep_kernel<<<80, 256, 0, stream>>>(W1, W2, W1p, W2p, pos, pos4, batch, range);
    knn_kernel<<<NSKIP / 4, 256, 0, stream>>>(pos4, range, pos_skip, batch_skip, idx3, w3);
    fused_mlp_kernel<<<NSKIP / 64, 256, 0, stream>>>(x, x_skip, idx3, w3,
                                                     W1p, b1, W2p, b2,
                                                     pos_skip, batch_skip, out);
}

// Round 9
// 118.555 us; speedup vs baseline: 1.0299x; 1.0299x over previous
//
#include <hip/hip_runtime.h>
#include <stdint.h>

#define NPTS   4096
#define NSKIP  16384
#define CCH    256
#define CSK    128
#define DIN    384
#define HDIM   256
#define BIGF   1e10f

typedef unsigned short u16;
typedef __attribute__((ext_vector_type(8))) short short8;
typedef __attribute__((ext_vector_type(4))) float floatx4;

__device__ __forceinline__ u16 f2bf(float f) {
    union { float f; uint32_t u; } c; c.f = f;
    uint32_t u = c.u;
    return (u16)((u + 0x7FFFu + ((u >> 16) & 1u)) >> 16);
}

// Pack (non-negative fp32 dist, idx) into a positive double whose numeric
// order == (dist, idx) lexicographic order (exact top_k tie semantics).
__device__ __forceinline__ double pkkey(float d, int j) {
    return __hiloint2double(__float_as_int(d), j);
}

// ---------------------------------------------------------------------------
// prep: blocks 0-47 pack W1 (KT=12), 48-79 pack W2 (KT=8) into MFMA
// B-fragment layout; blocks 48-63 also build pos4; block 0 builds ranges.
// ---------------------------------------------------------------------------
__global__ __launch_bounds__(256) void prep_kernel(
    const float* __restrict__ W1, const float* __restrict__ W2,
    u16* __restrict__ W1p, u16* __restrict__ W2p,
    const float* __restrict__ pos, float4* __restrict__ pos4,
    const int* __restrict__ batch, int* __restrict__ range)
{
    const int bid = blockIdx.x;
    const int t = threadIdx.x;

    const float* W = (bid < 48) ? W1 : W2;
    u16* Wp       = (bid < 48) ? W1p : W2p;
    const int KT  = (bid < 48) ? 12 : 8;
    const int g   = ((bid < 48) ? bid : (bid - 48)) * 256 + t;

    const int lane = g & 63;
    const int kt = (g >> 6) % KT;
    const int nt = (g >> 6) / KT;
    const int kbase = kt * 32 + (lane >> 4) * 8;
    const int n = nt * 16 + (lane & 15);
    u16 v[8];
#pragma unroll
    for (int j = 0; j < 8; ++j) v[j] = f2bf(W[(size_t)(kbase + j) * HDIM + n]);
#pragma unroll
    for (int j = 0; j < 8; ++j) Wp[(size_t)g * 8 + j] = v[j];

    if (bid >= 48 && bid < 64) {
        const int p = (bid - 48) * 256 + t;
        pos4[p] = make_float4(pos[p * 3 + 0], pos[p * 3 + 1], pos[p * 3 + 2], 0.0f);
    }

    if (bid == 0) {
        for (int j = t * 16; j < t * 16 + 16; ++j) {
            if (j == 0) {
                const int b0 = batch[0];
                for (int b = 0; b <= b0; ++b) range[b] = 0;
            } else {
                const int bp = batch[j - 1], bj = batch[j];
                for (int b = bp + 1; b <= bj; ++b) range[b] = j;
            }
            if (j == NPTS - 1) {
                const int bl = batch[NPTS - 1];
                for (int b = bl + 1; b <= 4; ++b) range[b] = NPTS;
            }
        }
    }
}

// ---------------------------------------------------------------------------
// KNN v4 (best-measured, R7): 32 threads per fine point (8 points / block,
// 2048 blocks -> full occupancy). Stride-32 float4 scan, branchless f64-key
// top-3 bubble, 5-step shfl_xor butterfly. _rn ops keep selection exact.
// ---------------------------------------------------------------------------
__global__ __launch_bounds__(256) void knn_kernel(
    const float4* __restrict__ pos4, const int* __restrict__ range,
    const float* __restrict__ pos_skip, const int* __restrict__ batch_skip,
    int* __restrict__ idx3, float* __restrict__ w3)
{
    const int t = threadIdx.x;
    const int i = blockIdx.x * 8 + (t >> 5);
    const int sub = t & 31;
    const int b = batch_skip[i];
    const int start = range[b], end = range[b + 1];

    const float px = pos_skip[i * 3 + 0];
    const float py = pos_skip[i * 3 + 1];
    const float pz = pos_skip[i * 3 + 2];

    const double BIGKEY = pkkey(BIGF, 0x7FFFFFFF);
    double k0 = BIGKEY, k1 = BIGKEY, k2 = BIGKEY;

    for (int j = start + sub; j < end; j += 32) {
        const float4 q = pos4[j];
        const float dx = __fsub_rn(px, q.x);
        const float dy = __fsub_rn(py, q.y);
        const float dz = __fsub_rn(pz, q.z);
        const float dd = __fadd_rn(__fadd_rn(__fmul_rn(dx, dx), __fmul_rn(dy, dy)),
                                   __fmul_rn(dz, dz));
        const double kk = pkkey(dd, j);
        const double u0 = fmax(k0, kk); k0 = fmin(k0, kk);
        const double u1 = fmax(k1, u0); k1 = fmin(k1, u0);
        k2 = fmin(k2, u1);
    }

#pragma unroll
    for (int m = 1; m < 32; m <<= 1) {
        const double o0 = __shfl_xor(k0, m);
        const double o1 = __shfl_xor(k1, m);
        const double o2 = __shfl_xor(k2, m);
        double u0 = fmax(k0, o0); k0 = fmin(k0, o0);
        double u1 = fmax(k1, u0); k1 = fmin(k1, u0);
        k2 = fmin(k2, u1);
        u1 = fmax(k1, o1); k1 = fmin(k1, o1);
        k2 = fmin(k2, u1);
        k2 = fmin(k2, o2);
    }

    if (sub == 0) {
        const float d0 = __int_as_float(__double2hiint(k0));
        const float d1 = __int_as_float(__double2hiint(k1));
        const float d2 = __int_as_float(__double2hiint(k2));
        const float w0 = 1.0f / fmaxf(d0, 1e-16f);
        const float w1 = 1.0f / fmaxf(d1, 1e-16f);
        const float w2 = 1.0f / fmaxf(d2, 1e-16f);
        const float inv = 1.0f / (w0 + w1 + w2);
        idx3[i * 3 + 0] = __double2loint(k0);
        idx3[i * 3 + 1] = __double2loint(k1);
        idx3[i * 3 + 2] = __double2loint(k2);
        w3[i * 3 + 0] = w0 * inv; w3[i * 3 + 1] = w1 * inv; w3[i * 3 + 2] = w2 * inv;
    }
}

// ---------------------------------------------------------------------------
// Fused MLP (best-measured, R7): 32 rows per block, 512 blocks (~6 blocks/CU).
// interp+concat -> LDS A(bf16)[32x392] -> MFMA GEMM1 (K=384) ->
// h(bf16)[32x264] -> MFMA GEMM2 (K=256) -> out (fp32) + tail copy.
// ---------------------------------------------------------------------------
__global__ __launch_bounds__(256) void fused_mlp_kernel(
    const float* __restrict__ x, const float* __restrict__ x_skip,
    const int* __restrict__ idx3, const float* __restrict__ w3,
    const u16* __restrict__ W1p, const float* __restrict__ b1,
    const u16* __restrict__ W2p, const float* __restrict__ b2,
    const float* __restrict__ pos_skip, const int* __restrict__ batch_skip,
    float* __restrict__ out)
{
    __shared__ u16 sA[32 * 392];   // 25088 B; reused as h[32][264]
    const int t = threadIdx.x;
    const int row0 = blockIdx.x * 32;

    // --- interp: 32 rows x 64 float4 (256 fp32 cols each) ---
#pragma unroll
    for (int k = 0; k < 8; ++k) {
        const int g = t + 256 * k;
        const int row = g >> 6, c4 = g & 63;
        const int R = row0 + row;
        const int i0 = idx3[R * 3 + 0], i1 = idx3[R * 3 + 1], i2 = idx3[R * 3 + 2];
        const float w0 = w3[R * 3 + 0], w1 = w3[R * 3 + 1], w2 = w3[R * 3 + 2];
        const float4 v0 = *(const float4*)(x + (size_t)i0 * CCH + c4 * 4);
        const float4 v1 = *(const float4*)(x + (size_t)i1 * CCH + c4 * 4);
        const float4 v2 = *(const float4*)(x + (size_t)i2 * CCH + c4 * 4);
        const float a  = w0 * v0.x + w1 * v1.x + w2 * v2.x;
        const float bq = w0 * v0.y + w1 * v1.y + w2 * v2.y;
        const float cq = w0 * v0.z + w1 * v1.z + w2 * v2.z;
        const float dq = w0 * v0.w + w1 * v1.w + w2 * v2.w;
        uint2 pk;
        pk.x = (uint32_t)f2bf(a)  | ((uint32_t)f2bf(bq) << 16);
        pk.y = (uint32_t)f2bf(cq) | ((uint32_t)f2bf(dq) << 16);
        *(uint2*)(sA + row * 392 + c4 * 4) = pk;
    }
    // --- skip copy: 32 rows x 32 float4 (128 fp32 cols each) ---
#pragma unroll
    for (int k = 0; k < 4; ++k) {
        const int g = t + 256 * k;
        const int row = g >> 5, c4 = g & 31;
        const float4 v = *(const float4*)(x_skip + (size_t)(row0 + row) * CSK + c4 * 4);
        uint2 pk;
        pk.x = (uint32_t)f2bf(v.x) | ((uint32_t)f2bf(v.y) << 16);
        pk.y = (uint32_t)f2bf(v.z) | ((uint32_t)f2bf(v.w) << 16);
        *(uint2*)(sA + row * 392 + CCH + c4 * 4) = pk;
    }
    __syncthreads();

    const int wave = t >> 6, lane = t & 63;
    const int quad = lane >> 4, ml = lane & 15;

    // --- GEMM1: A[32x384] @ W1 -> h[32x256] ---
    floatx4 acc[2][4] = {};
    {
        const u16* aA = sA + ml * 392 + quad * 8;
        for (int kt = 0; kt < 12; ++kt) {
            short8 a0 = *(const short8*)(aA + kt * 32);
            short8 a1 = *(const short8*)(aA + 16 * 392 + kt * 32);
#pragma unroll
            for (int nt = 0; nt < 4; ++nt) {
                const int ntile = wave * 4 + nt;
                short8 bfr = *(const short8*)(W1p + (size_t)((ntile * 12 + kt) * 64 + lane) * 8);
                acc[0][nt] = __builtin_amdgcn_mfma_f32_16x16x32_bf16(a0, bfr, acc[0][nt], 0, 0, 0);
                acc[1][nt] = __builtin_amdgcn_mfma_f32_16x16x32_bf16(a1, bfr, acc[1][nt], 0, 0, 0);
            }
        }
    }
    __syncthreads();

    // --- h = relu(acc + b1) -> LDS bf16 [32 x 264] ---
#pragma unroll
    for (int mt = 0; mt < 2; ++mt) {
#pragma unroll
        for (int nt = 0; nt < 4; ++nt) {
            const int n = (wave * 4 + nt) * 16 + ml;
            const float bv = b1[n];
#pragma unroll
            for (int r = 0; r < 4; ++r) {
                const int m = mt * 16 + quad * 4 + r;
                sA[m * 264 + n] = f2bf(fmaxf(acc[mt][nt][r] + bv, 0.0f));
            }
        }
    }
    __syncthreads();

    // --- GEMM2: h[32x256] @ W2 -> out (fp32) ---
    floatx4 acc2[2][4] = {};
    {
        const u16* aH = sA + ml * 264 + quad * 8;
        for (int kt = 0; kt < 8; ++kt) {
            short8 a0 = *(const short8*)(aH + kt * 32);
            short8 a1 = *(const short8*)(aH + 16 * 264 + kt * 32);
#pragma unroll
            for (int nt = 0; nt < 4; ++nt) {
                const int ntile = wave * 4 + nt;
                short8 bfr = *(const short8*)(W2p + (size_t)((ntile * 8 + kt) * 64 + lane) * 8);
                acc2[0][nt] = __builtin_amdgcn_mfma_f32_16x16x32_bf16(a0, bfr, acc2[0][nt], 0, 0, 0);
                acc2[1][nt] = __builtin_amdgcn_mfma_f32_16x16x32_bf16(a1, bfr, acc2[1][nt], 0, 0, 0);
            }
        }
    }

#pragma unroll
    for (int mt = 0; mt < 2; ++mt) {
#pragma unroll
        for (int nt = 0; nt < 4; ++nt) {
            const int n = (wave * 4 + nt) * 16 + ml;
            const float bv = b2[n];
#pragma unroll
            for (int r = 0; r < 4; ++r) {
                const int m = row0 + mt * 16 + quad * 4 + r;
                out[(size_t)m * HDIM + n] = fmaxf(acc2[mt][nt][r] + bv, 0.0f);
            }
        }
    }

    // --- tail: 128 flat elems per block ---
    if (t < 128) {
        const int e = blockIdx.x * 128 + t;
        const size_t base = (size_t)NSKIP * HDIM;
        if (e < NSKIP * 3) out[base + e] = pos_skip[e];
        else               out[base + e] = (float)batch_skip[e - NSKIP * 3];
    }
}

extern "C" void kernel_launch(void* const* d_in, const int* in_sizes, int n_in,
                              void* d_out, int out_size, void* d_ws, size_t ws_size,
                              hipStream_t stream) {
    const float* x         = (const float*)d_in[0];
    const float* pos       = (const float*)d_in[1];
    const int*   batch     = (const int*)d_in[2];
    const float* x_skip    = (const float*)d_in[3];
    const float* pos_skip  = (const float*)d_in[4];
    const int*   batch_skip= (const int*)d_in[5];
    const float* W1        = (const float*)d_in[6];
    const float* b1        = (const float*)d_in[7];
    const float* W2        = (const float*)d_in[8];
    const float* b2        = (const float*)d_in[9];
    float* out = (float*)d_out;

    // ws layout:
    char* ws = (char*)d_ws;
    u16*    W1p   = (u16*)ws;                      // 196608 B
    u16*    W2p   = (u16*)(ws + 196608);           // 131072 B
    int*    range = (int*)(ws + 327680);           // 32 B
    float4* pos4  = (float4*)(ws + 327712);        // 65536 B
    int*    idx3  = (int*)(ws + 393248);           // 196608 B
    float*  w3    = (float*)(ws + 589856);         // 196608 B

    prep_kernel<<<80, 256, 0, stream>>>(W1, W2, W1p, W2p, pos, pos4, batch, range);
    knn_kernel<<<NSKIP / 8, 256, 0, stream>>>(pos4, range, pos_skip, batch_skip, idx3, w3);
    fused_mlp_kernel<<<NSKIP / 32, 256, 0, stream>>>(x, x_skip, idx3, w3,
                                                     W1p, b1, W2p, b2,
                                                     pos_skip, batch_skip, out);
}